// Round 3
// baseline (132.353 us; speedup 1.0000x reference)
//
#include <hip/hip_runtime.h>

#define NQ 50000
#define NS 50000
#define MNB 32
#define KP 15
#define DF 64
#define NT 3125             // 16-query tiles
#define GRID 512            // 2 blocks/CU, ~6 tiles/block
#define WTS 968             // wt row stride in ushorts (960+8): b128 reads 2-way/quarter
#define WQR 32              // wq row stride in ushorts, XOR-swizzled chunks (no pad)

typedef __bf16 bf16x8 __attribute__((ext_vector_type(8)));
typedef float  f32x4  __attribute__((ext_vector_type(4)));
typedef float  f32x2  __attribute__((ext_vector_type(2)));

__device__ __forceinline__ unsigned short bf1(float f) {
    union { __bf16 h; unsigned short s; } r; r.h = (__bf16)f; return r.s;
}
__device__ __forceinline__ unsigned pk2(float a, float b) {   // v_cvt_pk_bf16_f32
    union { __bf16 h[2]; unsigned u; } r;
    r.h[0] = (__bf16)a; r.h[1] = (__bf16)b; return r.u;
}

// v_perm_b32 selectors: pool = {src1 bytes 0-3, src0 bytes 4-7}; builtin(a,b,s)
// has b as src1 (bytes 0-3). LO picks lo16 of b then lo16 of a; HI the hi16s.
#define PERM_LO 0x05040100u
#define PERM_HI 0x07060302u

// ---------------------------------------------------------------------------
// Prep: (blocks 0-29)   W [960][64] f32 -> bf16, B-fragment-swizzled; layout
//   wBf[(wv*30+ks)*64 + q*16 + cl] (per-GEMM-wave contiguous stream, 1KB/step).
//       (blocks 30+)    x [50000][64] f32 -> bf16 rows (xBf), 8 ch / thread.
// ---------------------------------------------------------------------------
__global__ __launch_bounds__(256) void conv_prep(const float* __restrict__ W,
                                                 uint4* __restrict__ wBf,
                                                 const float* __restrict__ x,
                                                 uint4* __restrict__ xBf) {
    const int b = blockIdx.x;
    if (b < 30) {
        const int chunk = b * 256 + threadIdx.x;   // < 7680
        const int tc = chunk >> 6, c = chunk & 63; // tc = 4*ks+q, c = wv*16+cl
        union { unsigned short s[8]; uint4 u; } pk;
        #pragma unroll
        for (int j = 0; j < 8; ++j)
            pk.s[j] = bf1(W[(size_t)(tc * 8 + j) * 64 + c]);
        const int ks = tc >> 2, qq = tc & 3, wvv = c >> 4, cll = c & 15;
        wBf[(wvv * 30 + ks) * 64 + qq * 16 + cll] = pk.u;
    } else {
        const int t = (b - 30) * 256 + threadIdx.x;   // uint4 chunk = 8 channels
        if (t < (NS * DF) / 8) {                      // 400000
            const float4* __restrict__ x4 = (const float4*)x;
            const float4 a = x4[t * 2];
            const float4 c = x4[t * 2 + 1];
            uint4 o;
            o.x = pk2(a.x, a.y); o.y = pk2(a.z, a.w);
            o.z = pk2(c.x, c.y); o.w = pk2(c.z, c.w);
            xBf[t] = o;
        }
    }
}

// ---------------------------------------------------------------------------
// Fused KPConv, tile-pipelined persistent blocks: 1024 threads, 16 queries /
// tile, each block processes tiles t = bid, bid+GRID, ... with wt double-
// buffered.  Per tile: ONE barrier; after it waves 0-3 run the tile's GEMM
// (reading wt[buf]) while waves 4-15 run the NEXT tile's phase A/B (writing
// wt[buf^1]).  Next-tile nb/qp issued before the barrier, dependent sp gather
// right after phase B -> gather latency hides under barrier-wait + GEMM.
// Safety: wq/ids are same-wave produce->consume (no barrier, as before);
// wt[buf] readers (GEMM t) vs next writers (phase A/B of t+2) are separated
// by barrier t+1.
// Phase A/B/GEMM internals as R1, plus: ids stored as u16 at slot sigma(p)
// (phase B reads all 8 ids as ONE ds_read_b128, broadcast within quarter);
// wq pad dropped -> 16B-chunk XOR swizzle (chunk' = chunk ^ (row&3)) keeps
// the af b128 read aligned with ~4-way (vs 8-way) bank conflicts; GEMM uses
// two accumulator chains (halves the 30-deep dependent MFMA chain).
// LDS = 61952 (wt x2) + 16384 (wq) + 1024 (ids) = 79360 B -> 2 blocks/CU.
// ---------------------------------------------------------------------------
__global__ __launch_bounds__(1024, 8) void kpconv_fused(
    const float* __restrict__ qp, const float* __restrict__ sp,
    const int* __restrict__ nb, const uint2* __restrict__ xb,
    const float* __restrict__ kpts, const uint4* __restrict__ wBf,
    float* __restrict__ out)
{
    __shared__ struct {
        __align__(16) unsigned short wt[2][16 * WTS];   // 61952 B (double buf)
        __align__(16) unsigned short wq[16][16 * WQR];  // 16384 B XOR-swizzled
        __align__(16) unsigned short ids[16][MNB];      //  1024 B u16 ids
    } sm;                                               // 79360 B

    const int tid  = threadIdx.x;
    const int lane = tid & 63;
    const int wv   = __builtin_amdgcn_readfirstlane(tid >> 6);  // 0-15, scalar
    const int kh = lane >> 5, m = lane & 31;
    const int cl = lane & 15, q = lane >> 4;

    // ---- prologue: prime tile t = blockIdx.x
    int t = blockIdx.x;
    int id; float qx, qy, qz, sx, sy, sz;
    {
        const int n = t * 16 + wv;
        id = nb[n * MNB + m];
        qx = qp[n * 3 + 0]; qy = qp[n * 3 + 1]; qz = qp[n * 3 + 2];
        sx = 1e6f; sy = 1e6f; sz = 1e6f;
        if (id < NS) { sx = sp[id * 3 + 0]; sy = sp[id * 3 + 1]; sz = sp[id * 3 + 2]; }
    }

    int buf = 0;
    while (t < NT) {
        const int n0 = t * 16;
        const int t2 = t + GRID;

        // ---- issue next-tile nb + qp NOW (independent of this tile)
        int id2 = NS; float qx2 = 0.f, qy2 = 0.f, qz2 = 0.f;
        if (t2 < NT) {
            const int n2 = t2 * 16 + wv;
            id2 = nb[n2 * MNB + m];
            qx2 = qp[n2 * 3 + 0]; qy2 = qp[n2 * 3 + 1]; qz2 = qp[n2 * 3 + 2];
        }

        // ---- phase A: lane (kh,m) -> kpoints kh*8..kh*8+7 for neighbor m
        const float rx = sx - qx, ry = sy - qy, rz = sz - qz;
        float wk[8], wmax = 0.0f;
        #pragma unroll
        for (int jj = 0; jj < 4; ++jj) {                   // pairs (k, k+4)
            const int ka = kh * 8 + jj;
            const int kb0 = ka + 4;
            const int kb = (kb0 < KP) ? kb0 : 0;           // k=15 -> phantom of k=0
            const f32x2 dx = (f32x2){rx, rx} - (f32x2){kpts[ka*3+0], kpts[kb*3+0]};
            const f32x2 dy = (f32x2){ry, ry} - (f32x2){kpts[ka*3+1], kpts[kb*3+1]};
            const f32x2 dz = (f32x2){rz, rz} - (f32x2){kpts[ka*3+2], kpts[kb*3+2]};
            const f32x2 d2 = dx * dx + dy * dy + dz * dz;  // v_pk_mul/fma
            const float wa = fmaxf(1.0f - __builtin_amdgcn_sqrtf(d2.x), 0.0f);
            const float wb = fmaxf(1.0f - __builtin_amdgcn_sqrtf(d2.y), 0.0f);
            wk[jj] = wa; wk[jj + 4] = wb;
            wmax = fmaxf(wmax, fmaxf(wa, wb));
        }
        // compaction (phantom k=15 activity == k=0's -> no false positives)
        const unsigned long long bal = __ballot(wmax > 0.0f);
        const unsigned comb = (unsigned)(bal & 0xFFFFFFFFull) | (unsigned)(bal >> 32);
        const int A = __popc(comb);                        // wave-uniform (SGPR)
        const bool act = (comb >> m) & 1u;
        const unsigned mlow = (1u << m) - 1u;
        const int p = act ? __popc(comb & mlow) : (A + __popc(~comb & mlow));
        const int s = (p & 3) * 8 + (p >> 2);              // K-slot sigma(p)
        const float gate = act ? 1.0f : 0.0f;              // zero inactive columns
        #pragma unroll
        for (int jj = 0; jj < 8; ++jj) {                   // unconditional: row 15
            const int row = kh * 8 + jj;
            const int off = row * WQR + ((((s >> 3) ^ (row & 3))) << 3) + (s & 7);
            sm.wq[wv][off] = bf1(wk[jj] * gate);           // finite junk
        }
        if (kh == 0) sm.ids[wv][s] = (unsigned short)(act ? id : 0);

        // ---- phase B: aggregation MFMA (same-wave LDS ordering, no barrier)
        union { uint4 u; bf16x8 v; } af;
        af.u = *(const uint4*)&sm.wq[wv][cl * WQR + ((q ^ (cl & 3)) << 3)];
        union { uint4 u; unsigned short h[8]; } iu;        // 8 ids, one b128
        iu.u = *(const uint4*)&sm.ids[wv][q * 8];          // slot q*8+j <-> p=4j+q
        uint2 r[8];
        #pragma unroll
        for (int j = 0; j < 8; ++j) {
            r[j] = (uint2){0u, 0u};
            if (4 * j < A)                                 // wave-uniform skip
                r[j] = xb[(size_t)iu.h[j] * 16 + cl];
        }
        union { uint4 u; bf16x8 v; } bfr[4];
        #pragma unroll
        for (int pr = 0; pr < 4; ++pr) {
            const uint2 e = r[2 * pr], o = r[2 * pr + 1];
            ((unsigned*)&bfr[0].u)[pr] = __builtin_amdgcn_perm(o.x, e.x, PERM_LO);
            ((unsigned*)&bfr[1].u)[pr] = __builtin_amdgcn_perm(o.x, e.x, PERM_HI);
            ((unsigned*)&bfr[2].u)[pr] = __builtin_amdgcn_perm(o.y, e.y, PERM_LO);
            ((unsigned*)&bfr[3].u)[pr] = __builtin_amdgcn_perm(o.y, e.y, PERM_HI);
        }
        const f32x4 zero = (f32x4){0.f, 0.f, 0.f, 0.f};
        f32x4 acc1[4];
        #pragma unroll
        for (int cb = 0; cb < 4; ++cb)
            acc1[cb] = __builtin_amdgcn_mfma_f32_16x16x32_bf16(af.v, bfr[cb].v, zero, 0, 0, 0);

        // D[row=4q+i][col=(cb,cl)] -> wt[buf^1? no: buf] ... this tile's buffer
        #pragma unroll
        for (int i = 0; i < 4; ++i) {
            const int k = q * 4 + i;
            if (k < KP) {
                uint2 pkd;
                pkd.x = pk2(acc1[0][i], acc1[1][i]);
                pkd.y = pk2(acc1[2][i], acc1[3][i]);
                *(uint2*)&sm.wt[buf][wv * WTS + k * 64 + cl * 4] = pkd;
            }
        }

        // ---- next-tile sp gather (id2 back by now; overlaps barrier + GEMM)
        float sx2 = 1e6f, sy2 = 1e6f, sz2 = 1e6f;
        if (id2 < NS) {
            sx2 = sp[id2 * 3 + 0]; sy2 = sp[id2 * 3 + 1]; sz2 = sp[id2 * 3 + 2];
        }

        __syncthreads();                                   // one barrier / tile

        // ---- GEMM: wave wv<4 -> out cols [wv*16,+16), 16 query rows of tile t
        if (wv < 4) {
            const unsigned short* wtb = sm.wt[buf];
            const uint4* wb = wBf + (wv * 30) * 64 + q * 16 + cl;
            f32x4 d0 = (f32x4){0.f, 0.f, 0.f, 0.f};
            f32x4 d1 = (f32x4){0.f, 0.f, 0.f, 0.f};
            #pragma unroll 5
            for (int ks = 0; ks < 30; ks += 2) {
                const bf16x8 a0 = *(const bf16x8*)&wtb[cl * WTS + ks * 32 + q * 8];
                const bf16x8 a1 = *(const bf16x8*)&wtb[cl * WTS + ks * 32 + 32 + q * 8];
                union { uint4 u; bf16x8 v; } b0, b1;
                b0.u = wb[ks * 64];
                b1.u = wb[ks * 64 + 64];
                d0 = __builtin_amdgcn_mfma_f32_16x16x32_bf16(a0, b0.v, d0, 0, 0, 0);
                d1 = __builtin_amdgcn_mfma_f32_16x16x32_bf16(a1, b1.v, d1, 0, 0, 0);
            }
            const f32x4 dacc = d0 + d1;
            #pragma unroll
            for (int i = 0; i < 4; ++i)
                out[(size_t)(n0 + q * 4 + i) * 64 + wv * 16 + cl] = dacc[i];
        }

        // ---- rotate
        buf ^= 1;
        t = t2;
        id = id2; qx = qx2; qy = qy2; qz = qz2; sx = sx2; sy = sy2; sz = sz2;
    }
}

// ---------------------------------------------------------------------------
extern "C" void kernel_launch(void* const* d_in, const int* in_sizes, int n_in,
                              void* d_out, int out_size, void* d_ws, size_t ws_size,
                              hipStream_t stream) {
    const float* qp   = (const float*)d_in[0];
    const float* sp   = (const float*)d_in[1];
    const int*   nb   = (const int*)d_in[2];
    const float* x    = (const float*)d_in[3];
    const float* kpts = (const float*)d_in[4];
    const float* W    = (const float*)d_in[5];
    float* out = (float*)d_out;

    uint4* wBf = (uint4*)d_ws;                          // 122880 B swizzled W
    uint4* xBf = (uint4*)((char*)d_ws + 122880);        // 6.4 MB bf16 features

    hipLaunchKernelGGL(conv_prep, dim3(30 + (NS * DF / 8 + 255) / 256), dim3(256),
                       0, stream, W, wBf, x, xBf);
    hipLaunchKernelGGL(kpconv_fused, dim3(GRID), dim3(1024), 0, stream,
                       qp, sp, nb, (const uint2*)xBf, kpts, wBf, out);
}

// Round 4
// 123.915 us; speedup vs baseline: 1.0681x; 1.0681x over previous
//
#include <hip/hip_runtime.h>

#define NQ 50000
#define NS 50000
#define MNB 32
#define KP 15
#define DF 64
#define NPW 12              // producer waves = queries per tile
#define NT 4167             // ceil(NQ / NPW)
#define GRID 512            // persistent: 2 blocks/CU
#define WTS 968             // wt row stride in ushorts (960+8 pad: 2-way on b128 reads)
#define WQS 40              // wq k-row stride in ushorts (32+8 pad: 4-way floor on b128)

typedef __bf16 bf16x8 __attribute__((ext_vector_type(8)));
typedef float  f32x4  __attribute__((ext_vector_type(4)));
typedef float  f32x2  __attribute__((ext_vector_type(2)));

__device__ __forceinline__ unsigned short bf1(float f) {
    union { __bf16 h; unsigned short s; } r; r.h = (__bf16)f; return r.s;
}
__device__ __forceinline__ unsigned pk2(float a, float b) {   // v_cvt_pk_bf16_f32
    union { __bf16 h[2]; unsigned u; } r;
    r.h[0] = (__bf16)a; r.h[1] = (__bf16)b; return r.u;
}

// v_perm_b32 selectors: pool = {src1 bytes 0-3, src0 bytes 4-7}; builtin(a,b,s)
// has b as src1 (bytes 0-3). LO picks lo16 of b then lo16 of a; HI the hi16s.
#define PERM_LO 0x05040100u
#define PERM_HI 0x07060302u

// ---------------------------------------------------------------------------
// Prep: (blocks 0-29)   W [960][64] f32 -> bf16, B-fragment-swizzled; layout
//   wBf[(g*30+ks)*64 + q*16 + cl] (per-consumer-wave contiguous 30KB stream).
//       (blocks 30+)    x [50000][64] f32 -> bf16 rows (xBf), 8 ch / thread.
// ---------------------------------------------------------------------------
__global__ __launch_bounds__(256) void conv_prep(const float* __restrict__ W,
                                                 uint4* __restrict__ wBf,
                                                 const float* __restrict__ x,
                                                 uint4* __restrict__ xBf) {
    const int b = blockIdx.x;
    if (b < 30) {
        const int chunk = b * 256 + threadIdx.x;   // < 7680
        const int tc = chunk >> 6, c = chunk & 63; // tc = 4*ks+q, c = g*16+cl
        union { unsigned short s[8]; uint4 u; } pk;
        #pragma unroll
        for (int j = 0; j < 8; ++j)
            pk.s[j] = bf1(W[(size_t)(tc * 8 + j) * 64 + c]);
        const int ks = tc >> 2, qq = tc & 3, g = c >> 4, cll = c & 15;
        wBf[(g * 30 + ks) * 64 + qq * 16 + cll] = pk.u;
    } else {
        const int t = (b - 30) * 256 + threadIdx.x;   // uint4 chunk = 8 channels
        if (t < (NS * DF) / 8) {                      // 400000
            const float4* __restrict__ x4 = (const float4*)x;
            const float4 a = x4[t * 2];
            const float4 c = x4[t * 2 + 1];
            uint4 o;
            o.x = pk2(a.x, a.y); o.y = pk2(a.z, a.w);
            o.z = pk2(c.x, c.y); o.w = pk2(c.z, c.w);
            xBf[t] = o;
        }
    }
}

// ---------------------------------------------------------------------------
// Fused KPConv, producer/consumer persistent blocks: 1024 threads, 12-query
// tiles.  Waves 0-11 ONLY produce (phase A/B for query t*12+wv, writing
// wt[buf] row wv); waves 12-15 ONLY consume (GEMM of tile t-GRID from
// wt[buf^1], N-chunk g = wv-12).  Steady state per tile:
//   [P: A/B(t)]  ||  [C: GEMM(t-1)]   ->  barrier  ->  buf ^= 1
// so the per-tile period is max(T_AB, T_GEMM), not T_AB + T_GEMM, and every
// resident wave issues every phase (no idle GEMM tail).  First iteration:
// consumers idle; one drain iteration at the end: producers idle.
// NO cross-tile prefetch registers (R3 spilled at the 256-VGPR cap).
// Phase A/B internals as R1; ids are u16 stored at slot sigma(p) so phase B
// reads all 8 gather ids as ONE ds_read_b128.  wt has 13 rows: rows 0-11 are
// queries, row 12 is zeroed once and broadcast-read for A-rows 12-15.
// LDS = 50336 (wt x2) + 15360 (wq) + 768 (ids) = 66464 B -> 2 blocks/CU.
// ---------------------------------------------------------------------------
__global__ __launch_bounds__(1024, 8) void kpconv_fused(
    const float* __restrict__ qp, const float* __restrict__ sp,
    const int* __restrict__ nb, const uint2* __restrict__ xb,
    const float* __restrict__ kpts, const uint4* __restrict__ wBf,
    float* __restrict__ out)
{
    __shared__ struct {
        __align__(16) unsigned short wt[2][13 * WTS];   // 50336 B (double buf)
        __align__(16) unsigned short wq[NPW][16 * WQS]; // 15360 B bf16 w[k][slot]
        __align__(16) unsigned short ids[NPW][MNB];     //   768 B u16 ids
    } sm;                                               // 66464 B

    const int tid  = threadIdx.x;
    const int lane = tid & 63;
    const int wv   = __builtin_amdgcn_readfirstlane(tid >> 6);  // 0-15, scalar
    const int kh = lane >> 5, m = lane & 31;
    const int cl = lane & 15, q = lane >> 4;

    // zero wt row 12 in both buffers (A-rows 12-15 broadcast-read it; never
    // written again; consumers first read after barrier #1 -> no extra sync)
    if (tid < 121) {
        ((uint4*)&sm.wt[0][12 * WTS])[tid] = (uint4){0u, 0u, 0u, 0u};
        ((uint4*)&sm.wt[1][12 * WTS])[tid] = (uint4){0u, 0u, 0u, 0u};
    }

    int buf = 0;
    for (int t = blockIdx.x; t < NT + GRID; t += GRID) {
        if (wv < NPW) {
            // ================= PRODUCER: phase A/B for query n ==============
            const int n = t * NPW + wv;
            if (t < NT && n < NQ) {
                // ---- phase A: lane (kh,m) -> kpoints kh*8..+7, neighbor m
                const int id = nb[n * MNB + m];
                const float qx = qp[n * 3 + 0], qy = qp[n * 3 + 1], qz = qp[n * 3 + 2];
                float sx = 1e6f, sy = 1e6f, sz = 1e6f;
                if (id < NS) { sx = sp[id * 3 + 0]; sy = sp[id * 3 + 1]; sz = sp[id * 3 + 2]; }
                const float rx = sx - qx, ry = sy - qy, rz = sz - qz;
                float wk[8], wmax = 0.0f;
                #pragma unroll
                for (int jj = 0; jj < 4; ++jj) {               // pairs (k, k+4)
                    const int ka = kh * 8 + jj;
                    const int kb0 = ka + 4;
                    const int kb = (kb0 < KP) ? kb0 : 0;       // k=15 -> phantom of k=0
                    const f32x2 dx = (f32x2){rx, rx} - (f32x2){kpts[ka*3+0], kpts[kb*3+0]};
                    const f32x2 dy = (f32x2){ry, ry} - (f32x2){kpts[ka*3+1], kpts[kb*3+1]};
                    const f32x2 dz = (f32x2){rz, rz} - (f32x2){kpts[ka*3+2], kpts[kb*3+2]};
                    const f32x2 d2 = dx * dx + dy * dy + dz * dz;
                    const float wa = fmaxf(1.0f - __builtin_amdgcn_sqrtf(d2.x), 0.0f);
                    const float wb = fmaxf(1.0f - __builtin_amdgcn_sqrtf(d2.y), 0.0f);
                    wk[jj] = wa; wk[jj + 4] = wb;
                    wmax = fmaxf(wmax, fmaxf(wa, wb));
                }
                // compaction (phantom k=15 activity == k=0's)
                const unsigned long long bal = __ballot(wmax > 0.0f);
                const unsigned comb = (unsigned)(bal & 0xFFFFFFFFull) | (unsigned)(bal >> 32);
                const int A = __popc(comb);                    // wave-uniform
                const bool act = (comb >> m) & 1u;
                const unsigned mlow = (1u << m) - 1u;
                const int p = act ? __popc(comb & mlow) : (A + __popc(~comb & mlow));
                const int s = (p & 3) * 8 + (p >> 2);          // K-slot sigma(p)
                const float gate = act ? 1.0f : 0.0f;
                #pragma unroll
                for (int jj = 0; jj < 8; ++jj)                 // unconditional: row 15
                    sm.wq[wv][(kh * 8 + jj) * WQS + s] = bf1(wk[jj] * gate);
                if (kh == 0) sm.ids[wv][s] = (unsigned short)(act ? id : 0);

                // ---- phase B: aggregation MFMA (same-wave LDS ordering)
                union { uint4 u; bf16x8 v; } af;
                af.u = *(const uint4*)&sm.wq[wv][cl * WQS + q * 8];
                union { uint4 u; unsigned short h[8]; } iu;    // 8 ids, one b128
                iu.u = *(const uint4*)&sm.ids[wv][q * 8];      // slot q*8+j <-> p=4j+q
                uint2 r[8];
                #pragma unroll
                for (int j = 0; j < 8; ++j) {
                    r[j] = (uint2){0u, 0u};
                    if (4 * j < A)                             // wave-uniform skip
                        r[j] = xb[(size_t)iu.h[j] * 16 + cl];
                }
                union { uint4 u; bf16x8 v; } bfr[4];
                #pragma unroll
                for (int pr = 0; pr < 4; ++pr) {
                    const uint2 e = r[2 * pr], o = r[2 * pr + 1];
                    ((unsigned*)&bfr[0].u)[pr] = __builtin_amdgcn_perm(o.x, e.x, PERM_LO);
                    ((unsigned*)&bfr[1].u)[pr] = __builtin_amdgcn_perm(o.x, e.x, PERM_HI);
                    ((unsigned*)&bfr[2].u)[pr] = __builtin_amdgcn_perm(o.y, e.y, PERM_LO);
                    ((unsigned*)&bfr[3].u)[pr] = __builtin_amdgcn_perm(o.y, e.y, PERM_HI);
                }
                const f32x4 zero = (f32x4){0.f, 0.f, 0.f, 0.f};
                f32x4 acc1[4];
                #pragma unroll
                for (int cb = 0; cb < 4; ++cb)
                    acc1[cb] = __builtin_amdgcn_mfma_f32_16x16x32_bf16(af.v, bfr[cb].v, zero, 0, 0, 0);

                // D[row=4q+i][col=(cb,cl)] -> wt[buf] row wv, kappa = k*64+cl*4+cb
                #pragma unroll
                for (int i = 0; i < 4; ++i) {
                    const int k = q * 4 + i;
                    if (k < KP) {
                        uint2 pkd;
                        pkd.x = pk2(acc1[0][i], acc1[1][i]);
                        pkd.y = pk2(acc1[2][i], acc1[3][i]);
                        *(uint2*)&sm.wt[buf][wv * WTS + k * 64 + cl * 4] = pkd;
                    }
                }
            }
        } else if (t > (int)blockIdx.x) {
            // ================= CONSUMER: GEMM of tile t-GRID ================
            const int tp = t - GRID;
            const int n0 = tp * NPW;
            const int g  = wv - NPW;                           // 0-3: N-chunk
            const unsigned short* wtb = sm.wt[buf ^ 1];
            const int arow = (cl < NPW) ? cl : NPW;            // rows 12-15: zero
            const uint4* wb = wBf + (g * 30) * 64 + q * 16 + cl;
            f32x4 d0 = (f32x4){0.f, 0.f, 0.f, 0.f};
            f32x4 d1 = (f32x4){0.f, 0.f, 0.f, 0.f};
            __builtin_amdgcn_s_setprio(1);
            #pragma unroll 5
            for (int ks = 0; ks < 30; ks += 2) {
                const bf16x8 a0 = *(const bf16x8*)&wtb[arow * WTS + ks * 32 + q * 8];
                const bf16x8 a1 = *(const bf16x8*)&wtb[arow * WTS + (ks + 1) * 32 + q * 8];
                union { uint4 u; bf16x8 v; } b0, b1;
                b0.u = wb[ks * 64];
                b1.u = wb[(ks + 1) * 64];
                d0 = __builtin_amdgcn_mfma_f32_16x16x32_bf16(a0, b0.v, d0, 0, 0, 0);
                d1 = __builtin_amdgcn_mfma_f32_16x16x32_bf16(a1, b1.v, d1, 0, 0, 0);
            }
            __builtin_amdgcn_s_setprio(0);
            const f32x4 dacc = d0 + d1;
            #pragma unroll
            for (int i = 0; i < 4; ++i) {
                const int rrow = q * 4 + i;
                const int n = n0 + rrow;
                if (rrow < NPW && n < NQ)
                    out[(size_t)n * 64 + g * 16 + cl] = dacc[i];
            }
        }
        __syncthreads();                                       // one barrier/tile
        buf ^= 1;
    }
}

// ---------------------------------------------------------------------------
extern "C" void kernel_launch(void* const* d_in, const int* in_sizes, int n_in,
                              void* d_out, int out_size, void* d_ws, size_t ws_size,
                              hipStream_t stream) {
    const float* qp   = (const float*)d_in[0];
    const float* sp   = (const float*)d_in[1];
    const int*   nb   = (const int*)d_in[2];
    const float* x    = (const float*)d_in[3];
    const float* kpts = (const float*)d_in[4];
    const float* W    = (const float*)d_in[5];
    float* out = (float*)d_out;

    uint4* wBf = (uint4*)d_ws;                          // 122880 B swizzled W
    uint4* xBf = (uint4*)((char*)d_ws + 122880);        // 6.4 MB bf16 features

    hipLaunchKernelGGL(conv_prep, dim3(30 + (NS * DF / 8 + 255) / 256), dim3(256),
                       0, stream, W, wBf, x, xBf);
    hipLaunchKernelGGL(kpconv_fused, dim3(GRID), dim3(1024), 0, stream,
                       qp, sp, nb, (const uint2*)xBf, kpts, wBf, out);
}